// Round 11
// baseline (146.568 us; speedup 1.0000x reference)
//
#include <hip/hip_runtime.h>

typedef __attribute__((ext_vector_type(8))) short short8;
typedef __attribute__((ext_vector_type(4))) float f32x4;
typedef __attribute__((ext_vector_type(2))) float f32x2;
typedef __attribute__((ext_vector_type(4))) unsigned int u32x4;

static __device__ __forceinline__ unsigned int fbits(float f) {
    union { float f; unsigned int u; } v; v.f = f; return v.u;
}
static __device__ __forceinline__ float bitsf(unsigned int u) {
    union { float f; unsigned int u; } v; v.u = u; return v.f;
}
// pack two f32 -> bf16 pair in ONE VALU op (v_perm_b32 byte select)
static __device__ __forceinline__ unsigned int pkbf(float lo, float hi) {
    return __builtin_amdgcn_perm(fbits(hi), fbits(lo), 0x07060302u);
}
static __device__ __forceinline__ float bflo(unsigned int u) { return bitsf(u << 16); }
static __device__ __forceinline__ float bfhi(unsigned int u) { return bitsf(u & 0xFFFF0000u); }
static __device__ __forceinline__ float leaky(float x) { return fmaxf(x, 0.01f * x); }
static __device__ __forceinline__ float rsqrt_nr(float x) {
    const float r = __builtin_amdgcn_rsqf(x);
    return r * (1.5f - (0.5f * x) * (r * r));
}
// packed f32 (VOP3P). _s: wave-uniform operand from SGPR pair (1 SGPR src max).
static __device__ __forceinline__ f32x2 pk_mul_s(f32x2 s, f32x2 v) {
    f32x2 d; asm("v_pk_mul_f32 %0, %1, %2" : "=v"(d) : "s"(s), "v"(v)); return d;
}
static __device__ __forceinline__ f32x2 pk_fma_s(f32x2 s, f32x2 v, f32x2 c) {
    f32x2 d; asm("v_pk_fma_f32 %0, %1, %2, %3" : "=v"(d) : "s"(s), "v"(v), "v"(c)); return d;
}
static __device__ __forceinline__ f32x2 pk_add_s(f32x2 s, f32x2 v) {
    f32x2 d; asm("v_pk_add_f32 %0, %1, %2" : "=v"(d) : "s"(s), "v"(v)); return d;
}
static __device__ __forceinline__ f32x2 pk_mul_v(f32x2 a, f32x2 b) {
    f32x2 d; asm("v_pk_mul_f32 %0, %1, %2" : "=v"(d) : "v"(a), "v"(b)); return d;
}
static __device__ __forceinline__ f32x2 pk_fma_v(f32x2 a, f32x2 b, f32x2 c) {
    f32x2 d; asm("v_pk_fma_f32 %0, %1, %2, %3" : "=v"(d) : "v"(a), "v"(b), "v"(c)); return d;
}
static __device__ __forceinline__ f32x2 leaky2(f32x2 x, f32x2 c001) {
    const f32x2 m = pk_mul_v(x, c001);
    f32x2 r; r.x = fmaxf(x.x, m.x); r.y = fmaxf(x.y, m.y); return r;
}

// ROUND 11: 2 ROWS PER LANE (r10 fused chain, unchanged algebra -- verified
// absmax 4.77e-7). Rationale: r0->r10 cut VALU busy 48->37us while wall stayed
// 53-57us across ALL structural variants (LDS volume, barriers, block size,
// occupancy, persistence). The one thing never varied: wave count (32768) and
// its per-wave fixed costs -- the weight-fragment preamble (~30 loads + ~100
// VALU, identical every round), wave setup/drain, serial GS ramp. Halving waves
// (2 rows/lane, block=512 rows, grid 4096) amortizes all of it 2x and doubles
// per-wave ILP (two independent row-chains).
//
// Layout/algebra (r10, verified): swapped-operand MFMA -- z^T = mfma(A=Whalf,
// B=h^T). Lane l, tile t holds B[k in {4q+j,4q+j+16}][row 16t+(l&15)]; C-layout
// output acc[r] = z[16t+(l&15)][{4q+r, 4q+r+16}] = SAME slot set as the next
// B-fragment -> leaky+gate+repack in registers, layers 2..4 with zero LDS.
// L4: per-lane pk-dot (8 features) + butterfly shfl_xor(16,32) over the 4
// q-lanes; lane keeps tile t==quad (then 16t+(l&15) == its own row). ONE
// __syncthreads per block. Set B identical with LDS rows +256.

struct Rot { float a0,a1,a2,c0,c1,c2,u0,u1,u2; };

static __device__ __forceinline__ Rot gs_l1(
    const float* __restrict__ vin, const float* __restrict__ win,
    const float* __restrict__ gW1, const float* __restrict__ gb1,
    int row, unsigned int* __restrict__ dst)
{
    const float v0 = vin[3*row+0], v1 = vin[3*row+1], v2 = vin[3*row+2];
    const float w0 = win[3*row+0], w1 = win[3*row+1], w2 = win[3*row+2];
    const float sv  = v0*v0 + v1*v1 + v2*v2;
    const float rnv = rsqrt_nr(sv);
    const float a0 = v0*rnv, a1 = v1*rnv, a2 = v2*rnv;            // v_on
    const float proj = w0*a0 + w1*a1 + w2*a2;
    const float o0 = w0 - proj*a0, o1 = w1 - proj*a1, o2 = w2 - proj*a2;
    const float sw  = o0*o0 + o1*o1 + o2*o2;
    const float rnw = rsqrt_nr(sw);
    const float c0 = o0*rnw, c1 = o1*rnw, c2 = o2*rnw;            // w_on
    const float u0 = a1*c2 - a2*c1;                               // u_on
    const float u1 = a2*c0 - a0*c2;
    const float u2 = a0*c1 - a1*c0;
    const float f0 = sv*rnv, f1 = proj, f2 = sw*rnw;

    const f32x2 c001 = {0.01f, 0.01f};
    const f32x2 fv0 = {f0,f0}, fv1 = {f1,f1}, fv2 = {f2,f2};
    unsigned int hp[16];
    #pragma unroll
    for (int j = 0; j < 16; ++j) {
        const f32x2 wp0 = {gW1[3*j+0], gW1[3*(j+16)+0]};
        const f32x2 wp1 = {gW1[3*j+1], gW1[3*(j+16)+1]};
        const f32x2 wp2 = {gW1[3*j+2], gW1[3*(j+16)+2]};
        const f32x2 bb  = {gb1[j], gb1[j+16]};
        f32x2 acc = pk_mul_s(wp0, fv0);
        acc = pk_fma_s(wp1, fv1, acc);
        acc = pk_fma_s(wp2, fv2, acc);
        acc = pk_add_s(bb, acc);
        const f32x2 h = leaky2(acc, c001);
        hp[j] = pkbf(h.x, h.y);                  // u32 j = (k=j lo, k=j+16 hi)
    }
    *(u32x4*)(dst+0)  = (u32x4){hp[0],hp[1],hp[2],hp[3]};
    *(u32x4*)(dst+4)  = (u32x4){hp[4],hp[5],hp[6],hp[7]};
    *(u32x4*)(dst+8)  = (u32x4){hp[8],hp[9],hp[10],hp[11]};
    *(u32x4*)(dst+12) = (u32x4){hp[12],hp[13],hp[14],hp[15]};
    return {a0,a1,a2,c0,c1,c2,u0,u1,u2};
}

// fused layers 2..4 for one 256-row set; LB = LDS row offset (0 or 256).
// Uses enclosing-scope: h1lds, wbase, i15, ko, quad, fW2lo/hi, fWd1lo/hi,
// cb2lo/hi, cbd1lo/hi, w00..w23 (Wd2 pairs), c001.
#define CHAIN234(LB, Y0, Y1, Y2)                                                   \
    {                                                                              \
        float s0k = 0.f, s1k = 0.f, s2k = 0.f;                                     \
        _Pragma("unroll")                                                          \
        for (int t = 0; t < 4; ++t) {                                              \
            const u32x4 bfr = *(const u32x4*)(                                     \
                &h1lds[((LB) + wbase + 16*t + i15)*20 + ko]);                      \
            const short8 bfrag = __builtin_bit_cast(short8, bfr);                  \
            const f32x4 accA = __builtin_amdgcn_mfma_f32_16x16x32_bf16(            \
                fW2lo, bfrag, cb2lo, 0, 0, 0);                                     \
            const f32x4 accB = __builtin_amdgcn_mfma_f32_16x16x32_bf16(            \
                fW2hi, bfrag, cb2hi, 0, 0, 0);                                     \
            u32x4 h2u;                                                             \
            _Pragma("unroll")                                                      \
            for (int r = 0; r < 4; ++r)                                            \
                h2u[r] = pkbf(leaky(accA[r]) * bflo(bfr[r]),                       \
                              leaky(accB[r]) * bfhi(bfr[r]));                      \
            const short8 h2frag = __builtin_bit_cast(short8, h2u);                 \
            const f32x4 accC = __builtin_amdgcn_mfma_f32_16x16x32_bf16(            \
                fWd1lo, h2frag, cbd1lo, 0, 0, 0);                                  \
            const f32x4 accD = __builtin_amdgcn_mfma_f32_16x16x32_bf16(            \
                fWd1hi, h2frag, cbd1hi, 0, 0, 0);                                  \
            f32x2 h30, h31, h32, h33;                                              \
            h30.x = leaky(accC[0]); h30.y = leaky(accD[0]);                        \
            h31.x = leaky(accC[1]); h31.y = leaky(accD[1]);                        \
            h32.x = leaky(accC[2]); h32.y = leaky(accD[2]);                        \
            h33.x = leaky(accC[3]); h33.y = leaky(accD[3]);                        \
            f32x2 P0 = pk_mul_v(w00, h30);                                         \
            f32x2 P1 = pk_mul_v(w10, h30);                                         \
            f32x2 P2 = pk_mul_v(w20, h30);                                         \
            P0 = pk_fma_v(w01, h31, P0); P1 = pk_fma_v(w11, h31, P1);              \
            P2 = pk_fma_v(w21, h31, P2);                                           \
            P0 = pk_fma_v(w02, h32, P0); P1 = pk_fma_v(w12, h32, P1);              \
            P2 = pk_fma_v(w22, h32, P2);                                           \
            P0 = pk_fma_v(w03, h33, P0); P1 = pk_fma_v(w13, h33, P1);              \
            P2 = pk_fma_v(w23, h33, P2);                                           \
            float s0 = P0.x + P0.y, s1 = P1.x + P1.y, s2 = P2.x + P2.y;            \
            s0 += __shfl_xor(s0, 16); s0 += __shfl_xor(s0, 32);                    \
            s1 += __shfl_xor(s1, 16); s1 += __shfl_xor(s1, 32);                    \
            s2 += __shfl_xor(s2, 16); s2 += __shfl_xor(s2, 32);                    \
            if (quad == t) { s0k = s0; s1k = s1; s2k = s2; }                       \
        }                                                                          \
        Y0 = s0k; Y1 = s1k; Y2 = s2k;                                              \
    }

__global__ __launch_bounds__(256, 4) void aero_mfma(
    const float* __restrict__ vin, const float* __restrict__ win,
    const float* __restrict__ gW1, const float* __restrict__ gb1,
    const float* __restrict__ gW2, const float* __restrict__ gb2,
    const float* __restrict__ gWd1, const float* __restrict__ gbd1,
    const float* __restrict__ gWd2, const float* __restrict__ gbd2,
    const float* __restrict__ gbias,
    float* __restrict__ out, int nrows)
{
    __shared__ unsigned int h1lds[512 * 20];   // 2 row-sets x 256 x 80B

    const int tid   = threadIdx.x;
    const int i15   = tid & 15;
    const int quad  = (tid >> 4) & 3;
    const int wbase = tid & 192;
    const int ko    = 4 * quad;

    const int base = blockIdx.x * 512;
    int rowA = base + tid;        if (rowA >= nrows) rowA = nrows - 1;
    int rowB = base + 256 + tid;  if (rowB >= nrows) rowB = nrows - 1;

    // ---- preamble (ONCE for both rows): swapped-layout weight frags + biases ----
    unsigned int aW2lo[4], aW2hi[4], aWd1lo[4], aWd1hi[4];
    {
        const float* p;
        p = gW2 + i15 * 32 + ko;
        { f32x4 xa = *(const f32x4*)p, xb = *(const f32x4*)(p + 16);
          #pragma unroll
          for (int j = 0; j < 4; ++j) aW2lo[j] = pkbf(xa[j], xb[j]); }
        p = gW2 + (16 + i15) * 32 + ko;
        { f32x4 xa = *(const f32x4*)p, xb = *(const f32x4*)(p + 16);
          #pragma unroll
          for (int j = 0; j < 4; ++j) aW2hi[j] = pkbf(xa[j], xb[j]); }
        p = gWd1 + i15 * 32 + ko;
        { f32x4 xa = *(const f32x4*)p, xb = *(const f32x4*)(p + 16);
          #pragma unroll
          for (int j = 0; j < 4; ++j) aWd1lo[j] = pkbf(xa[j], xb[j]); }
        p = gWd1 + (16 + i15) * 32 + ko;
        { f32x4 xa = *(const f32x4*)p, xb = *(const f32x4*)(p + 16);
          #pragma unroll
          for (int j = 0; j < 4; ++j) aWd1hi[j] = pkbf(xa[j], xb[j]); }
    }
    const short8 fW2lo  = __builtin_bit_cast(short8, (u32x4){aW2lo[0],  aW2lo[1],  aW2lo[2],  aW2lo[3]});
    const short8 fW2hi  = __builtin_bit_cast(short8, (u32x4){aW2hi[0],  aW2hi[1],  aW2hi[2],  aW2hi[3]});
    const short8 fWd1lo = __builtin_bit_cast(short8, (u32x4){aWd1lo[0], aWd1lo[1], aWd1lo[2], aWd1lo[3]});
    const short8 fWd1hi = __builtin_bit_cast(short8, (u32x4){aWd1hi[0], aWd1hi[1], aWd1hi[2], aWd1hi[3]});

    // Wd2 pairs as NAMED f32x2 (no arrays -> no scratch risk)
    f32x2 w00, w01, w02, w03, w10, w11, w12, w13, w20, w21, w22, w23;
    {
        f32x4 xa, xb;
        xa = *(const f32x4*)(gWd2 + 0*32 + ko); xb = *(const f32x4*)(gWd2 + 0*32 + ko + 16);
        w00.x = xa[0]; w00.y = xb[0]; w01.x = xa[1]; w01.y = xb[1];
        w02.x = xa[2]; w02.y = xb[2]; w03.x = xa[3]; w03.y = xb[3];
        xa = *(const f32x4*)(gWd2 + 1*32 + ko); xb = *(const f32x4*)(gWd2 + 1*32 + ko + 16);
        w10.x = xa[0]; w10.y = xb[0]; w11.x = xa[1]; w11.y = xb[1];
        w12.x = xa[2]; w12.y = xb[2]; w13.x = xa[3]; w13.y = xb[3];
        xa = *(const f32x4*)(gWd2 + 2*32 + ko); xb = *(const f32x4*)(gWd2 + 2*32 + ko + 16);
        w20.x = xa[0]; w20.y = xb[0]; w21.x = xa[1]; w21.y = xb[1];
        w22.x = xa[2]; w22.y = xb[2]; w23.x = xa[3]; w23.y = xb[3];
    }
    const f32x4 cb2lo  = *(const f32x4*)(gb2  + ko);
    const f32x4 cb2hi  = *(const f32x4*)(gb2  + 16 + ko);
    const f32x4 cbd1lo = *(const f32x4*)(gbd1 + ko);
    const f32x4 cbd1hi = *(const f32x4*)(gbd1 + 16 + ko);
    const f32x2 c001   = {0.01f, 0.01f};

    // ---- phase A for both rows (independent chains -> ILP), one barrier ----
    const Rot RA = gs_l1(vin, win, gW1, gb1, rowA, &h1lds[tid * 20]);
    const Rot RB = gs_l1(vin, win, gW1, gb1, rowB, &h1lds[(256 + tid) * 20]);
    __syncthreads();

    // ---- fused layers 2..4 in registers, per set ----
    float yA0, yA1, yA2, yB0, yB1, yB2;
    CHAIN234(0,   yA0, yA1, yA2);
    CHAIN234(256, yB0, yB1, yB2);

    const float bd20 = gbd2[0], bd21 = gbd2[1], bd22 = gbd2[2];
    const float gb0 = gbias[0], gb1v = gbias[1], gb2v = gbias[2];
    yA0 += bd20; yA1 += bd21; yA2 += bd22;
    yB0 += bd20; yB1 += bd21; yB2 += bd22;

    out[3*rowA + 0] = fmaf(RA.a0, yA0, fmaf(RA.c0, yA1, fmaf(RA.u0, yA2, gb0)));
    out[3*rowA + 1] = fmaf(RA.a1, yA0, fmaf(RA.c1, yA1, fmaf(RA.u1, yA2, gb1v)));
    out[3*rowA + 2] = fmaf(RA.a2, yA0, fmaf(RA.c2, yA1, fmaf(RA.u2, yA2, gb2v)));
    out[3*rowB + 0] = fmaf(RB.a0, yB0, fmaf(RB.c0, yB1, fmaf(RB.u0, yB2, gb0)));
    out[3*rowB + 1] = fmaf(RB.a1, yB0, fmaf(RB.c1, yB1, fmaf(RB.u1, yB2, gb1v)));
    out[3*rowB + 2] = fmaf(RB.a2, yB0, fmaf(RB.c2, yB1, fmaf(RB.u2, yB2, gb2v)));
}

extern "C" void kernel_launch(void* const* d_in, const int* in_sizes, int n_in,
                              void* d_out, int out_size, void* d_ws, size_t ws_size,
                              hipStream_t stream) {
    const float* v    = (const float*)d_in[0];
    const float* w    = (const float*)d_in[1];
    const float* W1   = (const float*)d_in[2];
    const float* b1   = (const float*)d_in[3];
    const float* W2   = (const float*)d_in[4];
    const float* b2   = (const float*)d_in[5];
    const float* Wd1  = (const float*)d_in[6];
    const float* bd1  = (const float*)d_in[7];
    const float* Wd2  = (const float*)d_in[8];
    const float* bd2  = (const float*)d_in[9];
    const float* bias = (const float*)d_in[10];

    const int nrows = in_sizes[0] / 3;
    dim3 block(256);
    dim3 grid((nrows + 511) / 512);
    hipLaunchKernelGGL(aero_mfma, grid, block, 0, stream,
                       v, w, W1, b1, W2, b2, Wd1, bd1, Wd2, bd2, bias,
                       (float*)d_out, nrows);
}